// Round 3
// baseline (214.279 us; speedup 1.0000x reference)
//
#include <hip/hip_runtime.h>
#include <hip/hip_fp16.h>
#include <math.h>

#define BB      2
#define C_CT    128
#define CB      32
#define NN      180
#define VV      13824      // 24*24*24
#define VOXB    64         // voxels per block
#define GR      4          // n-groups (one per wave)
#define NPG     45         // NN / GR
#define THREADS 256

// smem union (bytes):
//  phase 1-3: [0,16384) qw fp32 [32][128] ; [16384,49152) qpart fp32 [4][32][64]
//  phase 4-7: [0,23040) W half [180][64]  ; [24576,40960) Pacc half [4][32][64]
#define SMEM_BYTES 49152

__global__ __launch_bounds__(THREADS, 3)
void vmat_attn_kernel(const float* __restrict__ ct, const float* __restrict__ beam,
                      const float* __restrict__ qw, const float* __restrict__ qb,
                      const float* __restrict__ gam, const float* __restrict__ bet,
                      float* __restrict__ out)
{
    __shared__ __align__(16) unsigned char smem[SMEM_BYTES];
    __shared__ __align__(16) float l_part[GR][VOXB];
    __shared__ float l_final[VOXB];
    __shared__ float qb_s[CB], gam_s[CB], bet_s[CB];

    float*  qw_s  = (float*)smem;             // [32][128]
    float*  qpart = (float*)(smem + 16384);   // [g][o][vox] fp32
    __half* Wbuf  = (__half*)smem;            // [n][vox] f16
    __half* Pacc  = (__half*)(smem + 24576);  // [g][c][vox] f16

    const int t    = threadIdx.x;
    const int lane = t & 63;
    const int g    = t >> 6;      // wave id = n-group
    const int vq   = lane & 15;   // voxel quad (voxels vq*4..vq*4+3)
    const int cg   = lane >> 4;   // channel group (channels cg*8..cg*8+7)
    const int bid  = blockIdx.x;
    const int b    = bid / (VV / VOXB);
    const int v0   = (bid % (VV / VOXB)) * VOXB;

    // ---- phase 1: stage q_w + small params ----
    for (int i = t; i < CB * C_CT; i += THREADS) qw_s[i] = qw[i];
    if (t < CB) { qb_s[t] = qb[t]; gam_s[t] = gam[t]; bet_s[t] = bet[t]; }
    __syncthreads();

    // ---- phase 2: q projection partials; wave g covers cc in [32g, 32g+32) ----
    {
        const int v = v0 + lane;
        const float* ctp = ct + ((size_t)b * C_CT + g * 32) * VV + v;
        float ctv[32];
        #pragma unroll
        for (int j = 0; j < 32; ++j) ctv[j] = ctp[(size_t)j * VV];
        float qp[CB];
        #pragma unroll
        for (int o = 0; o < CB; ++o) qp[o] = 0.f;
        for (int j = 0; j < 32; ++j) {
            #pragma unroll
            for (int o = 0; o < CB; ++o)
                qp[o] = fmaf(qw_s[o * C_CT + g * 32 + j], ctv[j], qp[o]);
        }
        #pragma unroll
        for (int o = 0; o < CB; ++o) qpart[(g * CB + o) * VOXB + lane] = qp[o];
    }
    __syncthreads();

    // ---- phase 3: each lane gathers q[8 ch][4 vox] from partials ----
    float q[8][4];
    #pragma unroll
    for (int ci = 0; ci < 8; ++ci) {
        const int o = cg * 8 + ci;
        float4 a0 = *reinterpret_cast<const float4*>(&qpart[(0 * CB + o) * VOXB + vq * 4]);
        float4 a1 = *reinterpret_cast<const float4*>(&qpart[(1 * CB + o) * VOXB + vq * 4]);
        float4 a2 = *reinterpret_cast<const float4*>(&qpart[(2 * CB + o) * VOXB + vq * 4]);
        float4 a3 = *reinterpret_cast<const float4*>(&qpart[(3 * CB + o) * VOXB + vq * 4]);
        q[ci][0] = a0.x + a1.x + a2.x + a3.x + qb_s[o];
        q[ci][1] = a0.y + a1.y + a2.y + a3.y + qb_s[o];
        q[ci][2] = a0.z + a1.z + a2.z + a3.z + qb_s[o];
        q[ci][3] = a0.w + a1.w + a2.w + a3.w + qb_s[o];
    }
    __syncthreads();   // smem reused as W/Pacc below

    // ---- phase 4: fused logits + exp + weighted accum; 2-deep prefetch ----
    const float scale = 0.17677669529663687f;  // 32^-0.5
    float acc[8][4];
    #pragma unroll
    for (int ci = 0; ci < 8; ++ci)
        acc[ci][0] = acc[ci][1] = acc[ci][2] = acc[ci][3] = 0.f;
    float l0 = 0.f, l1 = 0.f, l2 = 0.f, l3 = 0.f;
    const float* bp0 = beam + (((size_t)b * NN + g * NPG) * CB + cg * 8) * VV + v0 + vq * 4;

    float4 kvA[8], kvB[8];
    auto loadK = [&](float4* kv, int i) {
        const float* bp = bp0 + (size_t)i * CB * VV;
        #pragma unroll
        for (int ci = 0; ci < 8; ++ci)
            kv[ci] = *reinterpret_cast<const float4*>(bp + (size_t)ci * VV);
    };
    auto computeK = [&](const float4* kv, int i) {
        float p0 = 0.f, p1 = 0.f, p2 = 0.f, p3 = 0.f;
        #pragma unroll
        for (int ci = 0; ci < 8; ++ci) {
            p0 = fmaf(q[ci][0], kv[ci].x, p0);
            p1 = fmaf(q[ci][1], kv[ci].y, p1);
            p2 = fmaf(q[ci][2], kv[ci].z, p2);
            p3 = fmaf(q[ci][3], kv[ci].w, p3);
        }
        p0 += __shfl_xor(p0, 16); p1 += __shfl_xor(p1, 16);
        p2 += __shfl_xor(p2, 16); p3 += __shfl_xor(p3, 16);
        p0 += __shfl_xor(p0, 32); p1 += __shfl_xor(p1, 32);
        p2 += __shfl_xor(p2, 32); p3 += __shfl_xor(p3, 32);
        float w0 = __expf(fminf(p0 * scale, 60.f));
        float w1 = __expf(fminf(p1 * scale, 60.f));
        float w2 = __expf(fminf(p2 * scale, 60.f));
        float w3 = __expf(fminf(p3 * scale, 60.f));
        if (cg == 0) {
            __half2* wp = reinterpret_cast<__half2*>(&Wbuf[(g * NPG + i) * VOXB + vq * 4]);
            wp[0] = __floats2half2_rn(w0, w1);
            wp[1] = __floats2half2_rn(w2, w3);
        }
        l0 += w0; l1 += w1; l2 += w2; l3 += w3;
        #pragma unroll
        for (int ci = 0; ci < 8; ++ci) {
            acc[ci][0] = fmaf(w0, kv[ci].x, acc[ci][0]);
            acc[ci][1] = fmaf(w1, kv[ci].y, acc[ci][1]);
            acc[ci][2] = fmaf(w2, kv[ci].z, acc[ci][2]);
            acc[ci][3] = fmaf(w3, kv[ci].w, acc[ci][3]);
        }
    };

    loadK(kvA, 0);
    #pragma unroll 1
    for (int i = 0; i < NPG - 1; i += 2) {
        loadK(kvB, i + 1);
        computeK(kvA, i);
        if (i + 2 < NPG) loadK(kvA, i + 2);
        computeK(kvB, i + 1);
    }
    computeK(kvA, NPG - 1);   // n=44 slot, loaded in last loop iteration

    // ---- phase 5: spill partials (f16) ----
    #pragma unroll
    for (int ci = 0; ci < 8; ++ci) {
        __half2* ap = reinterpret_cast<__half2*>(&Pacc[((g * CB) + cg * 8 + ci) * VOXB + vq * 4]);
        ap[0] = __floats2half2_rn(acc[ci][0], acc[ci][1]);
        ap[1] = __floats2half2_rn(acc[ci][2], acc[ci][3]);
    }
    if (cg == 0) {
        float4 lv; lv.x = l0; lv.y = l1; lv.z = l2; lv.w = l3;
        *reinterpret_cast<float4*>(&l_part[g][vq * 4]) = lv;
    }
    __syncthreads();

    // ---- phase 6: combine + LayerNorm + fused output (wave 0) ----
    if (t < VOXB) {
        float lt = l_part[0][t] + l_part[1][t] + l_part[2][t] + l_part[3][t];
        l_final[t] = lt;
        float inv_l = 1.f / lt;
        float f[CB], mu = 0.f;
        #pragma unroll
        for (int c = 0; c < CB; ++c) {
            f[c] = (__half2float(Pacc[(0 * CB + c) * VOXB + t]) +
                    __half2float(Pacc[(1 * CB + c) * VOXB + t]) +
                    __half2float(Pacc[(2 * CB + c) * VOXB + t]) +
                    __half2float(Pacc[(3 * CB + c) * VOXB + t])) * inv_l;
            mu += f[c];
        }
        mu *= (1.f / CB);
        float var = 0.f;
        #pragma unroll
        for (int c = 0; c < CB; ++c) { float d = f[c] - mu; var = fmaf(d, d, var); }
        float rs = rsqrtf(var * (1.f / CB) + 1e-5f);
        float* op = out + (size_t)b * CB * VV + v0 + t;
        #pragma unroll
        for (int c = 0; c < CB; ++c)
            op[(size_t)c * VV] = (f[c] - mu) * rs * gam_s[c] + bet_s[c];
    }
    __syncthreads();

    // ---- phase 7: normalized attn weights, aligned float4 stores ----
    {
        const int vv = t & 63;
        const int j  = t >> 6;
        const float inv_l = 1.f / l_final[vv];
        float* arow = out + (size_t)BB * CB * VV + ((size_t)b * VV + v0 + vv) * NN;
        const int q4_begin = j * 12;
        const int q4_end   = (j == 3) ? 45 : (j * 12 + 12);   // 45 float4 = 180 floats
        for (int q4 = q4_begin; q4 < q4_end; ++q4) {
            const int n0 = q4 * 4;
            float4 val;
            val.x = __half2float(Wbuf[(n0 + 0) * VOXB + vv]) * inv_l;
            val.y = __half2float(Wbuf[(n0 + 1) * VOXB + vv]) * inv_l;
            val.z = __half2float(Wbuf[(n0 + 2) * VOXB + vv]) * inv_l;
            val.w = __half2float(Wbuf[(n0 + 3) * VOXB + vv]) * inv_l;
            *reinterpret_cast<float4*>(arow + n0) = val;   // row base 720B = 16-aligned
        }
    }
}

extern "C" void kernel_launch(void* const* d_in, const int* in_sizes, int n_in,
                              void* d_out, int out_size, void* d_ws, size_t ws_size,
                              hipStream_t stream) {
    (void)in_sizes; (void)n_in; (void)out_size; (void)d_ws; (void)ws_size;
    const float* ct   = (const float*)d_in[0];
    const float* beam = (const float*)d_in[1];
    const float* qw   = (const float*)d_in[2];
    const float* qb   = (const float*)d_in[3];
    const float* gam  = (const float*)d_in[4];
    const float* bet  = (const float*)d_in[5];
    float* out = (float*)d_out;
    dim3 grid(BB * (VV / VOXB));   // 432 blocks
    vmat_attn_kernel<<<grid, THREADS, 0, stream>>>(ct, beam, qw, qb, gam, bet, out);
}

// Round 4
// 142.545 us; speedup vs baseline: 1.5032x; 1.5032x over previous
//
#include <hip/hip_runtime.h>
#include <math.h>

#define BB      2
#define C_CT    128
#define CB      32
#define NN      180
#define VV      13824      // 24*24*24
#define VOXB    64         // voxels per block
#define GR      4          // n-groups (one per wave)
#define NPG     45         // NN / GR
#define THREADS 256

typedef float vfloat4 __attribute__((ext_vector_type(4)));

__global__ __launch_bounds__(THREADS, 2)
void vmat_attn_kernel(const float* __restrict__ ct, const float* __restrict__ beam,
                      const float* __restrict__ qw, const float* __restrict__ qb,
                      const float* __restrict__ gam, const float* __restrict__ bet,
                      float* __restrict__ out)
{
    // Wbuf: phase1 = q_w staging [32][128]; phase4+ = unnorm weights W[n=180][vox=64] (46KB)
    __shared__ __align__(16) float Wbuf[NN * VOXB];
    // Pbuf: phase2 = q partials [g][o][vox]; phase5 = acc partials [g][c][vox] (32KB)
    __shared__ __align__(16) float Pbuf[GR][CB][VOXB];
    __shared__ __align__(16) float l_part[GR][VOXB];
    __shared__ float l_final[VOXB];
    __shared__ float qb_s[CB], gam_s[CB], bet_s[CB];

    const int t    = threadIdx.x;
    const int lane = t & 63;
    const int g    = t >> 6;      // wave id = n-group
    const int vq   = lane & 15;   // voxel quad (voxels vq*4..vq*4+3)
    const int cg   = lane >> 4;   // channel group (channels cg*8..cg*8+7)
    const int bid  = blockIdx.x;
    const int b    = bid / (VV / VOXB);
    const int v0   = (bid % (VV / VOXB)) * VOXB;

    // ---- phase 1: stage q_w + small params ----
    for (int i = t; i < CB * C_CT; i += THREADS) Wbuf[i] = qw[i];
    if (t < CB) { qb_s[t] = qb[t]; gam_s[t] = gam[t]; bet_s[t] = bet[t]; }
    __syncthreads();

    // ---- phase 2: q projection partials; wave g covers cc in [32g, 32g+32) ----
    {
        const int v = v0 + lane;
        const float* ctp = ct + ((size_t)b * C_CT + g * 32) * VV + v;
        float ctv[32];
        #pragma unroll
        for (int j = 0; j < 32; ++j) ctv[j] = ctp[(size_t)j * VV];
        float qp[CB];
        #pragma unroll
        for (int o = 0; o < CB; ++o) qp[o] = 0.f;
        for (int j = 0; j < 32; ++j) {
            #pragma unroll
            for (int o = 0; o < CB; ++o)
                qp[o] = fmaf(Wbuf[o * C_CT + g * 32 + j], ctv[j], qp[o]);
        }
        #pragma unroll
        for (int o = 0; o < CB; ++o) Pbuf[g][o][lane] = qp[o];
    }
    __syncthreads();

    // ---- phase 3: each lane gathers q[8 ch][4 vox] from partials ----
    float q[8][4];
    #pragma unroll
    for (int ci = 0; ci < 8; ++ci) {
        const int o = cg * 8 + ci;
        float4 a0 = *reinterpret_cast<const float4*>(&Pbuf[0][o][vq * 4]);
        float4 a1 = *reinterpret_cast<const float4*>(&Pbuf[1][o][vq * 4]);
        float4 a2 = *reinterpret_cast<const float4*>(&Pbuf[2][o][vq * 4]);
        float4 a3 = *reinterpret_cast<const float4*>(&Pbuf[3][o][vq * 4]);
        q[ci][0] = a0.x + a1.x + a2.x + a3.x + qb_s[o];
        q[ci][1] = a0.y + a1.y + a2.y + a3.y + qb_s[o];
        q[ci][2] = a0.z + a1.z + a2.z + a3.z + qb_s[o];
        q[ci][3] = a0.w + a1.w + a2.w + a3.w + qb_s[o];
    }
    __syncthreads();   // Pbuf/Wbuf reuse below

    // ---- phase 4: fused logits + exp + weighted accum; 2-deep ping-pong prefetch ----
    const float scale = 0.17677669529663687f;  // 32^-0.5
    float acc[8][4];
    #pragma unroll
    for (int ci = 0; ci < 8; ++ci)
        acc[ci][0] = acc[ci][1] = acc[ci][2] = acc[ci][3] = 0.f;
    float l0 = 0.f, l1 = 0.f, l2 = 0.f, l3 = 0.f;
    const float* bp0 = beam + (((size_t)b * NN + g * NPG) * CB + cg * 8) * VV + v0 + vq * 4;

    vfloat4 kvA[8], kvB[8];
    auto loadK = [&](vfloat4* kv, int i) {
        const float* bp = bp0 + (size_t)i * CB * VV;
        #pragma unroll
        for (int ci = 0; ci < 8; ++ci)
            kv[ci] = __builtin_nontemporal_load(
                reinterpret_cast<const vfloat4*>(bp + (size_t)ci * VV));
    };
    auto computeK = [&](const vfloat4* kv, int i) {
        float p0 = 0.f, p1 = 0.f, p2 = 0.f, p3 = 0.f;
        #pragma unroll
        for (int ci = 0; ci < 8; ++ci) {
            p0 = fmaf(q[ci][0], kv[ci].x, p0);
            p1 = fmaf(q[ci][1], kv[ci].y, p1);
            p2 = fmaf(q[ci][2], kv[ci].z, p2);
            p3 = fmaf(q[ci][3], kv[ci].w, p3);
        }
        p0 += __shfl_xor(p0, 16); p1 += __shfl_xor(p1, 16);
        p2 += __shfl_xor(p2, 16); p3 += __shfl_xor(p3, 16);
        p0 += __shfl_xor(p0, 32); p1 += __shfl_xor(p1, 32);
        p2 += __shfl_xor(p2, 32); p3 += __shfl_xor(p3, 32);
        float w0 = __expf(fminf(p0 * scale, 60.f));
        float w1 = __expf(fminf(p1 * scale, 60.f));
        float w2 = __expf(fminf(p2 * scale, 60.f));
        float w3 = __expf(fminf(p3 * scale, 60.f));
        if (cg == 0) {
            float4 wv; wv.x = w0; wv.y = w1; wv.z = w2; wv.w = w3;
            *reinterpret_cast<float4*>(&Wbuf[(g * NPG + i) * VOXB + vq * 4]) = wv;
        }
        l0 += w0; l1 += w1; l2 += w2; l3 += w3;
        #pragma unroll
        for (int ci = 0; ci < 8; ++ci) {
            acc[ci][0] = fmaf(w0, kv[ci].x, acc[ci][0]);
            acc[ci][1] = fmaf(w1, kv[ci].y, acc[ci][1]);
            acc[ci][2] = fmaf(w2, kv[ci].z, acc[ci][2]);
            acc[ci][3] = fmaf(w3, kv[ci].w, acc[ci][3]);
        }
    };

    loadK(kvA, 0);
    #pragma unroll 1
    for (int i = 0; i < NPG - 1; i += 2) {
        loadK(kvB, i + 1);          // issue next loads BEFORE consuming kvA
        computeK(kvA, i);
        if (i + 2 < NPG) loadK(kvA, i + 2);
        computeK(kvB, i + 1);
    }
    computeK(kvA, NPG - 1);   // n=44, loaded in last loop iteration

    // ---- phase 5: spill partials ----
    #pragma unroll
    for (int ci = 0; ci < 8; ++ci) {
        float4 av; av.x = acc[ci][0]; av.y = acc[ci][1]; av.z = acc[ci][2]; av.w = acc[ci][3];
        *reinterpret_cast<float4*>(&Pbuf[g][cg * 8 + ci][vq * 4]) = av;
    }
    if (cg == 0) {
        float4 lv; lv.x = l0; lv.y = l1; lv.z = l2; lv.w = l3;
        *reinterpret_cast<float4*>(&l_part[g][vq * 4]) = lv;
    }
    __syncthreads();

    // ---- phase 6: combine + LayerNorm + fused output (wave 0) ----
    if (t < VOXB) {
        float lt = l_part[0][t] + l_part[1][t] + l_part[2][t] + l_part[3][t];
        l_final[t] = lt;
        float inv_l = 1.f / lt;
        float f[CB], mu = 0.f;
        #pragma unroll
        for (int c = 0; c < CB; ++c) {
            f[c] = (Pbuf[0][c][t] + Pbuf[1][c][t] + Pbuf[2][c][t] + Pbuf[3][c][t]) * inv_l;
            mu += f[c];
        }
        mu *= (1.f / CB);
        float var = 0.f;
        #pragma unroll
        for (int c = 0; c < CB; ++c) { float d = f[c] - mu; var = fmaf(d, d, var); }
        float rs = rsqrtf(var * (1.f / CB) + 1e-5f);
        float* op = out + (size_t)b * CB * VV + v0 + t;
        #pragma unroll
        for (int c = 0; c < CB; ++c)
            op[(size_t)c * VV] = (f[c] - mu) * rs * gam_s[c] + bet_s[c];
    }
    __syncthreads();

    // ---- phase 7: normalized attn weights, aligned float4 stores ----
    {
        const int vv = t & 63;
        const int j  = t >> 6;
        const float inv_l = 1.f / l_final[vv];
        float* arow = out + (size_t)BB * CB * VV + ((size_t)b * VV + v0 + vv) * NN;
        const int q4_begin = j * 12;
        const int q4_end   = (j == 3) ? 45 : (j * 12 + 12);   // 45 float4 = 180 floats
        for (int q4 = q4_begin; q4 < q4_end; ++q4) {
            const int n0 = q4 * 4;
            float4 val;
            val.x = Wbuf[(n0 + 0) * VOXB + vv] * inv_l;
            val.y = Wbuf[(n0 + 1) * VOXB + vv] * inv_l;
            val.z = Wbuf[(n0 + 2) * VOXB + vv] * inv_l;
            val.w = Wbuf[(n0 + 3) * VOXB + vv] * inv_l;
            *reinterpret_cast<float4*>(arow + n0) = val;   // row base 720B = 16-aligned
        }
    }
}

extern "C" void kernel_launch(void* const* d_in, const int* in_sizes, int n_in,
                              void* d_out, int out_size, void* d_ws, size_t ws_size,
                              hipStream_t stream) {
    (void)in_sizes; (void)n_in; (void)out_size; (void)d_ws; (void)ws_size;
    const float* ct   = (const float*)d_in[0];
    const float* beam = (const float*)d_in[1];
    const float* qw   = (const float*)d_in[2];
    const float* qb   = (const float*)d_in[3];
    const float* gam  = (const float*)d_in[4];
    const float* bet  = (const float*)d_in[5];
    float* out = (float*)d_out;
    dim3 grid(BB * (VV / VOXB));   // 432 blocks
    vmat_attn_kernel<<<grid, THREADS, 0, stream>>>(ct, beam, qw, qb, gam, bet, out);
}